// Round 17
// baseline (4490.989 us; speedup 1.0000x reference)
//
#include <hip/hip_runtime.h>

#define N_NODES 100000
#define N_EDGES 1600000
#define N_GRAPHS 512
#define X_DIM 4
#define H 64
#define LAYERS 3
#define NUM_CLASS 3
#define NBLK 256            // partition blocks
#define EPB (N_EDGES / NBLK)  // 6250 edges per partition block
#define BKT_BITS 9
#define BKT_SZ 512          // nodes per bucket
#define NBKT ((N_NODES + BKT_SZ - 1) / BKT_SZ)  // 196
#define MHIST (NBKT * NBLK)  // 50176, divisible by 512
#define NCH (MHIST / 512)    // 98 scan chunks
#define LROW 72              // padded LDS row (shorts): 144 B, 16B-aligned rows
#define NCHUNKS ((N_NODES + 63) / 64)  // 1563
#define GBLK (N_NODES / 4)   // 25000 gather blocks (4 nodes each, exact)

typedef unsigned short ushort;
typedef short bf16x8 __attribute__((ext_vector_type(8)));
typedef unsigned short ush8 __attribute__((ext_vector_type(8)));
typedef float floatx4 __attribute__((ext_vector_type(4)));

__device__ __forceinline__ ushort f2bf(float v) {
    unsigned u = __float_as_uint(v);
    unsigned r = (u + 0x7fff + ((u >> 16) & 1)) >> 16;  // round-nearest-even
    return (ushort)r;
}
__device__ __forceinline__ float bf2f(ushort s) {
    return __uint_as_float(((unsigned)s) << 16);
}

// ---------------- phase A: bucket histogram + folded layer-1 precompute ----------------
__global__ __launch_bounds__(256) void hist1_kernel(
    const int* __restrict__ dst, int* __restrict__ histM,
    const float* __restrict__ Wemb, const float* __restrict__ bemb,
    const float* __restrict__ W1, const float* __restrict__ b1,
    const float* __restrict__ W2, const float* __restrict__ W3,
    const float* __restrict__ b3,
    float* __restrict__ G, float* __restrict__ C) {
    __shared__ int hist[NBKT];
    int t = threadIdx.x, b = blockIdx.x;
    for (int i = t; i < NBKT; i += 256) hist[i] = 0;
    __syncthreads();
    int e0 = b * EPB;
    for (int j = t; j < EPB; j += 256) {
        int d = dst[e0 + j];
        atomicAdd(hist + (d >> BKT_BITS), 1);
    }
    __syncthreads();
    for (int i = t; i < NBKT; i += 256) histM[i * NBLK + b] = hist[i];
    if (b == 0 && t < H) {
        int f = t;
        const float* Ws[3] = {W1, W2, W3};
#pragma unroll
        for (int wsel = 0; wsel < 3; ++wsel) {
            const float* W = Ws[wsel];
#pragma unroll
            for (int c = 0; c < X_DIM; ++c) {
                float g = 0.f;
                for (int k = 0; k < H; ++k) g += Wemb[c * H + k] * W[k * H + f];
                G[wsel * 256 + c * H + f] = g;
            }
            float cb = (wsel == 0) ? b1[f] : (wsel == 2) ? b3[f] : 0.f;
            for (int k = 0; k < H; ++k) cb += bemb[k] * W[k * H + f];
            C[wsel * H + f] = cb;
        }
    }
}

// ---------------- per-512-chunk inclusive scan over MHIST ----------------
__global__ __launch_bounds__(512) void gscan1_kernel(const int* __restrict__ v,
                                                     int* __restrict__ incl,
                                                     int* __restrict__ partials) {
    __shared__ int s[512];
    int tid = threadIdx.x;
    int i = blockIdx.x * 512 + tid;
    int x = (i < MHIST) ? v[i] : 0;
    s[tid] = x;
    for (int off = 1; off < 512; off <<= 1) {
        __syncthreads();
        int tv = (tid >= off) ? s[tid - off] : 0;
        __syncthreads();
        s[tid] += tv;
    }
    __syncthreads();
    if (i < MHIST) incl[i] = s[tid];
    if (tid == 511) partials[blockIdx.x] = s[tid];
}

// ---------------- phase B: partition edges (fused chunk-scan + ebase; LDS cursors) ----------------
// packed edge word: src(17 bits)<<15 | bf16(ea) low 15 bits (ea >= 0 so sign bit is 0)
// eb_dst stores the 9-bit in-bucket index only (bucket implied by position)
__global__ __launch_bounds__(256) void scatter1_kernel(
    const int* __restrict__ src, const int* __restrict__ dst, const float* __restrict__ ea,
    const int* __restrict__ histM, const int* __restrict__ incl,
    const int* __restrict__ partials,
    unsigned* __restrict__ eb_se, ushort* __restrict__ eb_dst, int* __restrict__ bkt_ptr) {
    __shared__ int coff[128];
    __shared__ int cur[NBKT];
    int t = threadIdx.x, b = blockIdx.x;
    if (t < 128) coff[t] = (t < NCH) ? partials[t] : 0;
    __syncthreads();
    for (int off = 1; off < 128; off <<= 1) {
        int tv = (t < 128 && t >= off) ? coff[t - off] : 0;
        __syncthreads();
        if (t < 128) coff[t] += tv;
        __syncthreads();
    }
    for (int i = t; i < NBKT; i += 256) {
        int idx = i * NBLK + b;
        int ch = idx >> 9;
        int off0 = (ch == 0) ? 0 : coff[ch - 1];
        cur[i] = incl[idx] - histM[idx] + off0;  // global exclusive prefix
    }
    __syncthreads();
    if (b == 0) {
        for (int i = t; i < NBKT; i += 256) bkt_ptr[i] = cur[i];
        if (t == 0) bkt_ptr[NBKT] = N_EDGES;
    }
    int e0 = b * EPB;
    for (int j = t; j < EPB; j += 256) {
        int e = e0 + j;
        int d = dst[e];
        int k = d >> BKT_BITS;
        int pos = atomicAdd(cur + k, 1);
        eb_se[pos] = ((unsigned)src[e] << 15) | (unsigned)f2bf(ea[e]);
        eb_dst[pos] = (ushort)(d & (BKT_SZ - 1));
    }
}

// ---------------- phase C: per-bucket CSR build + degw; also zero chunk flags ----------------
__global__ __launch_bounds__(512) void bucket_kernel(
    const int* __restrict__ bkt_ptr, const unsigned* __restrict__ eb_se,
    const ushort* __restrict__ eb_dst,
    int* __restrict__ row_ptr, float* __restrict__ degw, unsigned* __restrict__ epack,
    int* __restrict__ flags) {
    __shared__ int cnt[BKT_SZ];
    __shared__ float dws[BKT_SZ];
    __shared__ int s[BKT_SZ];
    __shared__ int cur[BKT_SZ];
    int k = blockIdx.x, t = threadIdx.x;
    // zero the per-chunk arrival flags for the fused layers (covers every launch)
    int fg = k * 512 + t;
    if (fg < NCHUNKS) flags[fg] = 0;
    int base = k << BKT_BITS;
    int nn = N_NODES - base;
    if (nn > BKT_SZ) nn = BKT_SZ;
    cnt[t] = 0;
    dws[t] = 0.0f;
    __syncthreads();
    int beg = bkt_ptr[k], end = bkt_ptr[k + 1];
    for (int j = beg + t; j < end; j += 512) {
        int d = eb_dst[j];
        atomicAdd(cnt + d, 1);
        atomicAdd(dws + d, __uint_as_float((eb_se[j] & 0x7FFFu) << 16));
    }
    __syncthreads();
    s[t] = cnt[t];
    for (int off = 1; off < 512; off <<= 1) {
        __syncthreads();
        int tv = (t >= off) ? s[t - off] : 0;
        __syncthreads();
        s[t] += tv;
    }
    __syncthreads();
    int rstart = beg + s[t] - cnt[t];
    if (t < nn) {
        row_ptr[base + t] = rstart;
        degw[base + t] = dws[t];
        cur[t] = rstart;
    }
    __syncthreads();
    for (int j = beg + t; j < end; j += 512) {
        unsigned se = eb_se[j];
        int d = eb_dst[j];
        int pos = atomicAdd(cur + d, 1);
        epack[pos] = se;
    }
    if (k == NBKT - 1 && t == 0) row_ptr[N_NODES] = N_EDGES;
}

// ---------------- layer 1 (fused xgather + combine), wave = 1 node ----------------
__global__ __launch_bounds__(256) void layer1_kernel(
    const int* __restrict__ row_ptr, const unsigned* __restrict__ epack,
    const float* __restrict__ x, const float* __restrict__ degw,
    const float* __restrict__ G, const float* __restrict__ C,
    ushort* __restrict__ h) {
    int n = blockIdx.x * 4 + (threadIdx.x >> 6);
    if (n >= N_NODES) return;
    int lane = threadIdx.x & 63;
    float Gr[12], Cr[3];
#pragma unroll
    for (int i = 0; i < 12; ++i) Gr[i] = G[(i >> 2) * 256 + (i & 3) * 64 + lane];
#pragma unroll
    for (int i = 0; i < 3; ++i) Cr[i] = C[i * 64 + lane];
    int q2 = lane >> 1, cp = lane & 1;
    int beg = row_ptr[n], end = row_ptr[n + 1];
    float a0 = 0.f, a1 = 0.f;
    for (int j = beg; j < end; j += 32) {
        int jk = j + q2;
        unsigned w = (jk < end) ? epack[jk] : 0u;
        float2 xv = *(const float2*)&x[(size_t)(w >> 15) * X_DIM + cp * 2];
        float e = __uint_as_float((w & 0x7FFFu) << 16);
        a0 += e * xv.x;
        a1 += e * xv.y;
    }
#pragma unroll
    for (int mask = 2; mask <= 32; mask <<= 1) {
        a0 += __shfl_xor(a0, mask);
        a1 += __shfl_xor(a1, mask);
    }
    float mv0 = __shfl(a0, 0), mv1 = __shfl(a1, 0);
    float mv2 = __shfl(a0, 1), mv3 = __shfl(a1, 1);
    floatx4 xr = *(const floatx4*)&x[(size_t)n * X_DIM];
    float dw = degw[n];
    float t1 = mv0 * Gr[0] + mv1 * Gr[1] + mv2 * Gr[2] + mv3 * Gr[3];
    float t2 = xr[0] * Gr[4] + xr[1] * Gr[5] + xr[2] * Gr[6] + xr[3] * Gr[7];
    float t3 = xr[0] * Gr[8] + xr[1] * Gr[9] + xr[2] * Gr[10] + xr[3] * Gr[11];
    float v = t1 + dw * Cr[0] + t3 + Cr[2] - (t2 + Cr[1]) * dw;
    h[(size_t)n * H + lane] = f2bf(fmaxf(v, 0.0f));
}

// ---------------- fused gather + MFMA lin via last-arriver (no grid sync) ----------------
// Grid = 25000 blocks; wave = 1 node (full gather TLP). After a block's 4 m-rows are
// written: release fence + flag atomicAdd. The last arriver of each 64-node chunk
// (16 blocks; 8 for the tail) acquires and runs the MFMA epilogue, writing hout.
// Flags accumulate across both layers: winner at old == mult*cnt-1 (mult = 1, then 2).
__global__ __launch_bounds__(256) void fusedGL_kernel(
    const ushort* __restrict__ hin, ushort* __restrict__ m, ushort* __restrict__ hout,
    const int* __restrict__ row_ptr, const unsigned* __restrict__ epack,
    const float* __restrict__ degw,
    const float* __restrict__ W1, const float* __restrict__ bias1,
    const float* __restrict__ W2, const float* __restrict__ W3,
    const float* __restrict__ bias3,
    int* __restrict__ flags, int mult) {
    __shared__ alignas(16) ushort ah[64 * LROW];
    __shared__ alignas(16) ushort am[64 * LROW];
    __shared__ int winner_s;
    int t = threadIdx.x;
    int wv = t >> 6, lane = t & 63;
    // ---- gather phase: node n = blockIdx*4 + wv (exact: GBLK*4 == N_NODES) ----
    {
        int n = blockIdx.x * 4 + wv;
        int q = lane >> 3, s = lane & 7;
        int beg = row_ptr[n], end = row_ptr[n + 1];
        float acc[8] = {0.f, 0.f, 0.f, 0.f, 0.f, 0.f, 0.f, 0.f};
        for (int j = beg; j < end; j += 32) {
            unsigned w[4];
#pragma unroll
            for (int k = 0; k < 4; ++k) {
                int jk = j + k * 8 + q;
                w[k] = (jk < end) ? epack[jk] : 0u;
            }
            ush8 av[4];
#pragma unroll
            for (int k = 0; k < 4; ++k)
                av[k] = *(const ush8*)&hin[(size_t)(w[k] >> 15) * H + s * 8];
#pragma unroll
            for (int k = 0; k < 4; ++k) {
                float e = __uint_as_float((w[k] & 0x7FFFu) << 16);
#pragma unroll
                for (int i = 0; i < 8; ++i)
                    acc[i] += e * bf2f((ushort)av[k][i]);
            }
        }
#pragma unroll
        for (int i = 0; i < 8; ++i) {
            acc[i] += __shfl_xor(acc[i], 8);
            acc[i] += __shfl_xor(acc[i], 16);
            acc[i] += __shfl_xor(acc[i], 32);
        }
        if (q == 0) {
            ush8 r;
#pragma unroll
            for (int i = 0; i < 8; ++i) r[i] = (short)f2bf(acc[i]);
            *(ush8*)&m[(size_t)n * H + s * 8] = r;
        }
    }
    __syncthreads();  // all block stores drained to this XCD's L2
    int chunk = blockIdx.x >> 4;
    if (t == 0) {
        __threadfence();  // release: flush block's m rows to the coherent point
        int cntb = GBLK - (chunk << 4);
        if (cntb > 16) cntb = 16;
        int old = atomicAdd(flags + chunk, 1);
        winner_s = (old == mult * cntb - 1) ? 1 : 0;
    }
    __syncthreads();
    if (!winner_s) return;
    __threadfence();  // acquire: invalidate stale cached m lines
    // ---- MFMA phase for this chunk ----
    int quad = lane >> 4, m16 = lane & 15;
    int fcol = wv * 16 + m16;
    bf16x8 B[3][2][2];  // [weight][khalf][hi/lo]
    const float* Ws[3] = {W1, W2, W3};
#pragma unroll
    for (int wsel = 0; wsel < 3; ++wsel) {
#pragma unroll
        for (int kh = 0; kh < 2; ++kh) {
#pragma unroll
            for (int j = 0; j < 8; ++j) {
                float w = Ws[wsel][(kh * 32 + quad * 8 + j) * H + fcol];
                ushort hi = f2bf(w);
                B[wsel][kh][0][j] = (short)hi;
                B[wsel][kh][1][j] = (short)f2bf(w - bf2f(hi));
            }
        }
    }
    float bb1 = bias1[fcol], bb3 = bias3[fcol];
    int nbase = chunk * 64;
    for (int v = t; v < 64 * 8; v += 256) {
        int nl = v >> 3, k0 = (v & 7) * 8;
        int n = nbase + nl;
        ush8 vh = {0, 0, 0, 0, 0, 0, 0, 0};
        ush8 vm = {0, 0, 0, 0, 0, 0, 0, 0};
        if (n < N_NODES) {
            vh = *(const ush8*)&hin[(size_t)n * H + k0];
            vm = *(const ush8*)&m[(size_t)n * H + k0];
        }
        *(ush8*)&ah[nl * LROW + k0] = vh;
        *(ush8*)&am[nl * LROW + k0] = vm;
    }
    __syncthreads();
#pragma unroll
    for (int ng = 0; ng < 4; ++ng) {
        int abase = (ng * 16 + m16) * LROW + quad * 8;
        bf16x8 Ah0 = *(const bf16x8*)&ah[abase];
        bf16x8 Ah1 = *(const bf16x8*)&ah[abase + 32];
        bf16x8 Am0 = *(const bf16x8*)&am[abase];
        bf16x8 Am1 = *(const bf16x8*)&am[abase + 32];
        floatx4 acc1 = {0.f, 0.f, 0.f, 0.f};
        floatx4 acc2 = {0.f, 0.f, 0.f, 0.f};
        floatx4 acc3 = {0.f, 0.f, 0.f, 0.f};
        acc1 = __builtin_amdgcn_mfma_f32_16x16x32_bf16(Am0, B[0][0][0], acc1, 0, 0, 0);
        acc1 = __builtin_amdgcn_mfma_f32_16x16x32_bf16(Am0, B[0][0][1], acc1, 0, 0, 0);
        acc1 = __builtin_amdgcn_mfma_f32_16x16x32_bf16(Am1, B[0][1][0], acc1, 0, 0, 0);
        acc1 = __builtin_amdgcn_mfma_f32_16x16x32_bf16(Am1, B[0][1][1], acc1, 0, 0, 0);
        acc2 = __builtin_amdgcn_mfma_f32_16x16x32_bf16(Ah0, B[1][0][0], acc2, 0, 0, 0);
        acc2 = __builtin_amdgcn_mfma_f32_16x16x32_bf16(Ah0, B[1][0][1], acc2, 0, 0, 0);
        acc2 = __builtin_amdgcn_mfma_f32_16x16x32_bf16(Ah1, B[1][1][0], acc2, 0, 0, 0);
        acc2 = __builtin_amdgcn_mfma_f32_16x16x32_bf16(Ah1, B[1][1][1], acc2, 0, 0, 0);
        acc3 = __builtin_amdgcn_mfma_f32_16x16x32_bf16(Ah0, B[2][0][0], acc3, 0, 0, 0);
        acc3 = __builtin_amdgcn_mfma_f32_16x16x32_bf16(Ah0, B[2][0][1], acc3, 0, 0, 0);
        acc3 = __builtin_amdgcn_mfma_f32_16x16x32_bf16(Ah1, B[2][1][0], acc3, 0, 0, 0);
        acc3 = __builtin_amdgcn_mfma_f32_16x16x32_bf16(Ah1, B[2][1][1], acc3, 0, 0, 0);
        int nrow = nbase + ng * 16 + quad * 4;
#pragma unroll
        for (int r = 0; r < 4; ++r) {
            int n = nrow + r;
            if (n < N_NODES) {
                float dw = degw[n];
                float v = acc1[r] + dw * bb1 + acc3[r] + bb3 - acc2[r] * dw;
                hout[(size_t)n * H + fcol] = f2bf(fmaxf(v, 0.0f));
            }
        }
    }
}

// ---------------- fused mean-pool + MLP head (batch is sorted) ----------------
__device__ __forceinline__ int lower_bound(const int* __restrict__ arr, int n, int key) {
    int lo = 0, hi = n;
    while (lo < hi) {
        int mid = (lo + hi) >> 1;
        if (arr[mid] < key) lo = mid + 1; else hi = mid;
    }
    return lo;
}

__global__ __launch_bounds__(256) void poolhead_kernel(
    const ushort* __restrict__ h, const int* __restrict__ batch,
    const float* __restrict__ Wf1, const float* __restrict__ bf1v,
    const float* __restrict__ Wf2, const float* __restrict__ bf2v,
    float* __restrict__ out) {
    __shared__ float psum[4][H];
    __shared__ float gx[H];
    __shared__ float hid[2 * H];
    int g = blockIdx.x, t = threadIdx.x;
    int s = lower_bound(batch, N_NODES, g);
    int e = lower_bound(batch, N_NODES, g + 1);
    int lane = t & 63, wv = t >> 6;
    int o = lane & 7;
    int nd = t >> 3;
    float acc[8] = {0.f, 0.f, 0.f, 0.f, 0.f, 0.f, 0.f, 0.f};
    for (int n = s + nd; n < e; n += 32) {
        ush8 v = *(const ush8*)&h[(size_t)n * H + o * 8];
#pragma unroll
        for (int i = 0; i < 8; ++i) acc[i] += bf2f((ushort)v[i]);
    }
#pragma unroll
    for (int i = 0; i < 8; ++i) {
        acc[i] += __shfl_xor(acc[i], 8);
        acc[i] += __shfl_xor(acc[i], 16);
        acc[i] += __shfl_xor(acc[i], 32);
    }
    if (lane < 8) {
#pragma unroll
        for (int i = 0; i < 8; ++i) psum[wv][o * 8 + i] = acc[i];
    }
    __syncthreads();
    if (t < H) {
        float c = (float)(e - s);
        gx[t] = (psum[0][t] + psum[1][t] + psum[2][t] + psum[3][t]) / fmaxf(c, 1.0f);
    }
    __syncthreads();
    if (t < 2 * H) {
        float acc2 = bf1v[t];
        for (int k = 0; k < H; ++k) acc2 += gx[k] * Wf1[k * 2 * H + t];
        hid[t] = fmaxf(acc2, 0.0f);
    }
    __syncthreads();
    if (t < NUM_CLASS) {
        float o2 = bf2v[t];
        for (int k = 0; k < 2 * H; ++k) o2 += hid[k] * Wf2[k * NUM_CLASS + t];
        out[g * NUM_CLASS + t] = o2;
    }
}

extern "C" void kernel_launch(void* const* d_in, const int* in_sizes, int n_in,
                              void* d_out, int out_size, void* d_ws, size_t ws_size,
                              hipStream_t stream) {
    const float* x    = (const float*)d_in[0];
    const int*  ei    = (const int*)d_in[1];
    const int*  batch = (const int*)d_in[2];
    const float* ea   = (const float*)d_in[3];
    const float* Wemb = (const float*)d_in[4];
    const float* bemb = (const float*)d_in[5];
    const float* pW1  = (const float*)d_in[6];
    const float* pb1  = (const float*)d_in[7];
    const float* pW2  = (const float*)d_in[8];
    const float* pW3  = (const float*)d_in[9];
    const float* pb3  = (const float*)d_in[10];
    const float* Wf1  = (const float*)d_in[11];
    const float* bf1v = (const float*)d_in[12];
    const float* Wf2  = (const float*)d_in[13];
    const float* bf2v = (const float*)d_in[14];
    float* out = (float*)d_out;

    const int* src = ei;
    const int* dst = ei + N_EDGES;

    // ---- workspace layout ----
    const size_t NH = (size_t)N_NODES * H;
    char* p = (char*)d_ws;
    ushort* hA      = (ushort*)p;            p += NH * 2;               // 12.8 MB
    ushort* hB      = (ushort*)p;            p += NH * 2;               // 12.8 MB
    ushort* m       = (ushort*)p;            p += NH * 2;               // 12.8 MB
    unsigned* epack = (unsigned*)p;          p += (size_t)N_EDGES * 4;  // 6.4 MB
    int*   histM    = (int*)p;               p += MHIST * 4;
    int*   incl     = (int*)p;               p += MHIST * 4;
    int*   partials = (int*)p;               p += 512 * 4;
    int*   bkt_ptr  = (int*)p;               p += (NBKT + 1) * 4;
    int*   row_ptr  = (int*)p;               p += (N_NODES + 1) * 4;
    float* degw     = (float*)p;             p += N_NODES * 4;
    float* Gbuf     = (float*)p;             p += 3 * 256 * 4;
    float* Cbuf     = (float*)p;             p += 3 * 64 * 4;
    int*   flags    = (int*)p;               p += NCHUNKS * 4;
    // staging overlays m/hB (both dead until the fused layers; build completes first)
    unsigned* eb_se = (unsigned*)m;          // 6.4 MB (m region: 12.8 MB)
    ushort*  eb_dst = (ushort*)hB;           // 3.2 MB (hB region: 12.8 MB)

    // ---- CSR build: 4 dispatches ----
    hist1_kernel<<<NBLK, 256, 0, stream>>>(dst, histM, Wemb, bemb, pW1, pb1, pW2, pW3, pb3,
                                           Gbuf, Cbuf);
    gscan1_kernel<<<MHIST / 512, 512, 0, stream>>>(histM, incl, partials);
    scatter1_kernel<<<NBLK, 256, 0, stream>>>(src, dst, ea, histM, incl, partials,
                                              eb_se, eb_dst, bkt_ptr);
    bucket_kernel<<<NBKT, 512, 0, stream>>>(bkt_ptr, eb_se, eb_dst, row_ptr, degw, epack,
                                            flags);

    // ---- layer 1: fused x-gather + combine -> hA ----
    layer1_kernel<<<(N_NODES + 3) / 4, 256, 0, stream>>>(row_ptr, epack, x, degw,
                                                         Gbuf, Cbuf, hA);

    // ---- layers 2,3: fused gather + last-arriver MFMA, ping-pong hA <-> hB ----
    fusedGL_kernel<<<GBLK, 256, 0, stream>>>(
        hA, m, hB, row_ptr, epack, degw,
        pW1 + (size_t)1 * H * H, pb1 + (size_t)1 * H,
        pW2 + (size_t)1 * H * H, pW3 + (size_t)1 * H * H, pb3 + (size_t)1 * H,
        flags, 1);
    fusedGL_kernel<<<GBLK, 256, 0, stream>>>(
        hB, m, hA, row_ptr, epack, degw,
        pW1 + (size_t)2 * H * H, pb1 + (size_t)2 * H,
        pW2 + (size_t)2 * H * H, pW3 + (size_t)2 * H * H, pb3 + (size_t)2 * H,
        flags, 2);

    poolhead_kernel<<<N_GRAPHS, 256, 0, stream>>>(hA, batch, Wf1, bf1v, Wf2, bf2v, out);
}

// Round 18
// 308.699 us; speedup vs baseline: 14.5481x; 14.5481x over previous
//
#include <hip/hip_runtime.h>

#define N_NODES 100000
#define N_EDGES 1600000
#define N_GRAPHS 512
#define X_DIM 4
#define H 64
#define LAYERS 3
#define NUM_CLASS 3
#define NBLK 256            // partition blocks
#define EPB (N_EDGES / NBLK)  // 6250 edges per partition block
#define BKT_BITS 9
#define BKT_SZ 512          // nodes per bucket
#define NBKT ((N_NODES + BKT_SZ - 1) / BKT_SZ)  // 196
#define MHIST (NBKT * NBLK)  // 50176
#define LROW 72              // padded LDS row (shorts): 144 B, 16B-aligned rows
#define NCHUNKS ((N_NODES + 63) / 64)  // 1563
#define LINC_GRID 521        // 1563 / 521 = exactly 3 chunks per block

typedef unsigned short ushort;
typedef short bf16x8 __attribute__((ext_vector_type(8)));
typedef unsigned short ush8 __attribute__((ext_vector_type(8)));
typedef float floatx4 __attribute__((ext_vector_type(4)));

__device__ __forceinline__ ushort f2bf(float v) {
    unsigned u = __float_as_uint(v);
    unsigned r = (u + 0x7fff + ((u >> 16) & 1)) >> 16;  // round-nearest-even
    return (ushort)r;
}
__device__ __forceinline__ float bf2f(ushort s) {
    return __uint_as_float(((unsigned)s) << 16);
}

// ---------------- phase A: bucket histogram + folded layer-1 precompute ----------------
// block 0 lanes<64 also compute G_i = Wemb@W_i (4x64), C_i = bemb@W_i (+bias)
__global__ __launch_bounds__(256) void hist1_kernel(
    const int* __restrict__ dst, int* __restrict__ histM,
    const float* __restrict__ Wemb, const float* __restrict__ bemb,
    const float* __restrict__ W1, const float* __restrict__ b1,
    const float* __restrict__ W2, const float* __restrict__ W3,
    const float* __restrict__ b3,
    float* __restrict__ G, float* __restrict__ C) {
    __shared__ int hist[NBKT];
    int t = threadIdx.x, b = blockIdx.x;
    for (int i = t; i < NBKT; i += 256) hist[i] = 0;
    __syncthreads();
    int e0 = b * EPB;
    for (int j = t; j < EPB; j += 256) {
        int d = dst[e0 + j];
        atomicAdd(hist + (d >> BKT_BITS), 1);
    }
    __syncthreads();
    for (int i = t; i < NBKT; i += 256) histM[i * NBLK + b] = hist[i];
    if (b == 0 && t < H) {
        int f = t;
        const float* Ws[3] = {W1, W2, W3};
#pragma unroll
        for (int wsel = 0; wsel < 3; ++wsel) {
            const float* W = Ws[wsel];
#pragma unroll
            for (int c = 0; c < X_DIM; ++c) {
                float g = 0.f;
                for (int k = 0; k < H; ++k) g += Wemb[c * H + k] * W[k * H + f];
                G[wsel * 256 + c * H + f] = g;
            }
            float cb = (wsel == 0) ? b1[f] : (wsel == 2) ? b3[f] : 0.f;
            for (int k = 0; k < H; ++k) cb += bemb[k] * W[k * H + f];
            C[wsel * H + f] = cb;
        }
    }
}

// ---------------- phase B: partition edges; scan computed IN-BLOCK from histM ----------------
// Each block b: thread t (bucket t) streams histM row t (256 ints, L2-resident),
// accumulating rowSum and the column-prefix up to b. Block-wide scan of rowSums
// gives the global exclusive prefix; cur[i] = rowPrefExcl[i] + colPref[i][b].
// packed edge word: src(17)<<15 | bf16(ea) low 15 bits. eb_dst = 9-bit local idx.
__global__ __launch_bounds__(256) void scatter1_kernel(
    const int* __restrict__ src, const int* __restrict__ dst, const float* __restrict__ ea,
    const int* __restrict__ histM,
    unsigned* __restrict__ eb_se, ushort* __restrict__ eb_dst, int* __restrict__ bkt_ptr) {
    __shared__ int rowpref[256];
    __shared__ int cur[NBKT];
    int t = threadIdx.x, b = blockIdx.x;
    int rowSum = 0, colpref = 0;
    if (t < NBKT) {
        const int* row = histM + t * NBLK;
        for (int c = 0; c < NBLK; ++c) {
            int v = row[c];
            rowSum += v;
            if (c < b) colpref += v;
        }
    }
    rowpref[t] = (t < NBKT) ? rowSum : 0;
    for (int off = 1; off < 256; off <<= 1) {
        __syncthreads();
        int tv = (t >= off) ? rowpref[t - off] : 0;
        __syncthreads();
        rowpref[t] += tv;
    }
    __syncthreads();
    if (t < NBKT) {
        int excl = (t == 0) ? 0 : rowpref[t - 1];
        cur[t] = excl + colpref;
        if (b == 0) bkt_ptr[t] = cur[t];
    }
    if (b == 0 && t == 0) bkt_ptr[NBKT] = N_EDGES;
    __syncthreads();
    int e0 = b * EPB;
    for (int j = t; j < EPB; j += 256) {
        int e = e0 + j;
        int d = dst[e];
        int k = d >> BKT_BITS;
        int pos = atomicAdd(cur + k, 1);
        eb_se[pos] = ((unsigned)src[e] << 15) | (unsigned)f2bf(ea[e]);
        eb_dst[pos] = (ushort)(d & (BKT_SZ - 1));
    }
}

// ---------------- phase C: per-bucket CSR build + degw (LDS atomics only) ----------------
__global__ __launch_bounds__(512) void bucket_kernel(
    const int* __restrict__ bkt_ptr, const unsigned* __restrict__ eb_se,
    const ushort* __restrict__ eb_dst,
    int* __restrict__ row_ptr, float* __restrict__ degw, unsigned* __restrict__ epack) {
    __shared__ int cnt[BKT_SZ];
    __shared__ float dws[BKT_SZ];
    __shared__ int s[BKT_SZ];
    __shared__ int cur[BKT_SZ];
    int k = blockIdx.x, t = threadIdx.x;
    int base = k << BKT_BITS;
    int nn = N_NODES - base;
    if (nn > BKT_SZ) nn = BKT_SZ;
    cnt[t] = 0;
    dws[t] = 0.0f;
    __syncthreads();
    int beg = bkt_ptr[k], end = bkt_ptr[k + 1];
    for (int j = beg + t; j < end; j += 512) {
        int d = eb_dst[j];
        atomicAdd(cnt + d, 1);
        atomicAdd(dws + d, __uint_as_float((eb_se[j] & 0x7FFFu) << 16));
    }
    __syncthreads();
    s[t] = cnt[t];
    for (int off = 1; off < 512; off <<= 1) {
        __syncthreads();
        int tv = (t >= off) ? s[t - off] : 0;
        __syncthreads();
        s[t] += tv;
    }
    __syncthreads();
    int rstart = beg + s[t] - cnt[t];
    if (t < nn) {
        row_ptr[base + t] = rstart;
        degw[base + t] = dws[t];
        cur[t] = rstart;
    }
    __syncthreads();
    for (int j = beg + t; j < end; j += 512) {
        unsigned se = eb_se[j];
        int d = eb_dst[j];
        int pos = atomicAdd(cur + d, 1);
        epack[pos] = se;
    }
    if (k == NBKT - 1 && t == 0) row_ptr[N_NODES] = N_EDGES;
}

// ---------------- layer 1 (fused xgather + combine), wave = 1 node ----------------
// h = bf16(relu(mx@G1 + dw*C1 + x@G3 + C3 - (x@G2 + C2)*dw)), mx = sum_in ea*x[src]
__global__ __launch_bounds__(256) void layer1_kernel(
    const int* __restrict__ row_ptr, const unsigned* __restrict__ epack,
    const float* __restrict__ x, const float* __restrict__ degw,
    const float* __restrict__ G, const float* __restrict__ C,
    ushort* __restrict__ h) {
    int n = blockIdx.x * 4 + (threadIdx.x >> 6);
    if (n >= N_NODES) return;
    int lane = threadIdx.x & 63;
    float Gr[12], Cr[3];
#pragma unroll
    for (int i = 0; i < 12; ++i) Gr[i] = G[(i >> 2) * 256 + (i & 3) * 64 + lane];
#pragma unroll
    for (int i = 0; i < 3; ++i) Cr[i] = C[i * 64 + lane];
    int q2 = lane >> 1, cp = lane & 1;
    int beg = row_ptr[n], end = row_ptr[n + 1];
    float a0 = 0.f, a1 = 0.f;
    for (int j = beg; j < end; j += 32) {
        int jk = j + q2;
        unsigned w = (jk < end) ? epack[jk] : 0u;
        float2 xv = *(const float2*)&x[(size_t)(w >> 15) * X_DIM + cp * 2];
        float e = __uint_as_float((w & 0x7FFFu) << 16);
        a0 += e * xv.x;
        a1 += e * xv.y;
    }
#pragma unroll
    for (int mask = 2; mask <= 32; mask <<= 1) {
        a0 += __shfl_xor(a0, mask);
        a1 += __shfl_xor(a1, mask);
    }
    float mv0 = __shfl(a0, 0), mv1 = __shfl(a1, 0);
    float mv2 = __shfl(a0, 1), mv3 = __shfl(a1, 1);
    floatx4 xr = *(const floatx4*)&x[(size_t)n * X_DIM];
    float dw = degw[n];
    float t1 = mv0 * Gr[0] + mv1 * Gr[1] + mv2 * Gr[2] + mv3 * Gr[3];
    float t2 = xr[0] * Gr[4] + xr[1] * Gr[5] + xr[2] * Gr[6] + xr[3] * Gr[7];
    float t3 = xr[0] * Gr[8] + xr[1] * Gr[9] + xr[2] * Gr[10] + xr[3] * Gr[11];
    float v = t1 + dw * Cr[0] + t3 + Cr[2] - (t2 + Cr[1]) * dw;
    h[(size_t)n * H + lane] = f2bf(fmaxf(v, 0.0f));
}

// ---------------- gather: m[d] = bf16(sum_in ea*h[src]) ----------------
// wave = 1 node; lane = q*8+s: edge-slot q (0..7), feature octet s
__global__ __launch_bounds__(256) void gather_kernel(
    const int* __restrict__ row_ptr, const unsigned* __restrict__ epack,
    const ushort* __restrict__ h, ushort* __restrict__ m) {
    int n = blockIdx.x * 4 + (threadIdx.x >> 6);
    if (n >= N_NODES) return;
    int lane = threadIdx.x & 63;
    int q = lane >> 3, s = lane & 7;
    int beg = row_ptr[n], end = row_ptr[n + 1];
    float acc[8] = {0.f, 0.f, 0.f, 0.f, 0.f, 0.f, 0.f, 0.f};
    for (int j = beg; j < end; j += 32) {
        unsigned w[4];
#pragma unroll
        for (int k = 0; k < 4; ++k) {
            int jk = j + k * 8 + q;
            w[k] = (jk < end) ? epack[jk] : 0u;
        }
        ush8 av[4];
#pragma unroll
        for (int k = 0; k < 4; ++k)
            av[k] = *(const ush8*)&h[(size_t)(w[k] >> 15) * H + s * 8];
#pragma unroll
        for (int k = 0; k < 4; ++k) {
            float e = __uint_as_float((w[k] & 0x7FFFu) << 16);
#pragma unroll
            for (int i = 0; i < 8; ++i)
                acc[i] += e * bf2f((ushort)av[k][i]);
        }
    }
#pragma unroll
    for (int i = 0; i < 8; ++i) {
        acc[i] += __shfl_xor(acc[i], 8);
        acc[i] += __shfl_xor(acc[i], 16);
        acc[i] += __shfl_xor(acc[i], 32);
    }
    if (q == 0) {
        ush8 r;
#pragma unroll
        for (int i = 0; i < 8; ++i) r[i] = (short)f2bf(acc[i]);
        *(ush8*)&m[(size_t)n * H + s * 8] = r;
    }
}

// ---------------- linC: h = bf16(relu(m@W1 + dw*b1 + h@W3 + b3 - (h@W2)*dw))  in-place ------
// Persistent blocks; B-fragments in registers once per block; stages h+m tiles in LDS.
__global__ __launch_bounds__(256) void linC_kernel(
    ushort* __restrict__ h, const ushort* __restrict__ m,
    const float* __restrict__ degw,
    const float* __restrict__ W1, const float* __restrict__ bias1,
    const float* __restrict__ W2, const float* __restrict__ W3,
    const float* __restrict__ bias3) {
    __shared__ alignas(16) ushort ah[64 * LROW];
    __shared__ alignas(16) ushort am[64 * LROW];
    int t = threadIdx.x;
    int wv = t >> 6, lane = t & 63;
    int quad = lane >> 4, m16 = lane & 15;
    int f = wv * 16 + m16;
    bf16x8 B[3][2][2];  // [weight][khalf][hi/lo]
    const float* Ws[3] = {W1, W2, W3};
#pragma unroll
    for (int wsel = 0; wsel < 3; ++wsel) {
#pragma unroll
        for (int kh = 0; kh < 2; ++kh) {
#pragma unroll
            for (int j = 0; j < 8; ++j) {
                float w = Ws[wsel][(kh * 32 + quad * 8 + j) * H + f];
                ushort hi = f2bf(w);
                B[wsel][kh][0][j] = (short)hi;
                B[wsel][kh][1][j] = (short)f2bf(w - bf2f(hi));
            }
        }
    }
    float bb1 = bias1[f], bb3 = bias3[f];
    for (int chunk = blockIdx.x; chunk < NCHUNKS; chunk += gridDim.x) {
        int nbase = chunk * 64;
        __syncthreads();  // protect LDS reuse across chunk iterations
        for (int v = t; v < 64 * 8; v += 256) {
            int nl = v >> 3, k0 = (v & 7) * 8;
            int n = nbase + nl;
            ush8 vh = {0, 0, 0, 0, 0, 0, 0, 0};
            ush8 vm = {0, 0, 0, 0, 0, 0, 0, 0};
            if (n < N_NODES) {
                vh = *(const ush8*)&h[(size_t)n * H + k0];
                vm = *(const ush8*)&m[(size_t)n * H + k0];
            }
            *(ush8*)&ah[nl * LROW + k0] = vh;
            *(ush8*)&am[nl * LROW + k0] = vm;
        }
        __syncthreads();
#pragma unroll
        for (int ng = 0; ng < 4; ++ng) {
            int abase = (ng * 16 + m16) * LROW + quad * 8;
            bf16x8 Ah0 = *(const bf16x8*)&ah[abase];
            bf16x8 Ah1 = *(const bf16x8*)&ah[abase + 32];
            bf16x8 Am0 = *(const bf16x8*)&am[abase];
            bf16x8 Am1 = *(const bf16x8*)&am[abase + 32];
            floatx4 acc1 = {0.f, 0.f, 0.f, 0.f};
            floatx4 acc2 = {0.f, 0.f, 0.f, 0.f};
            floatx4 acc3 = {0.f, 0.f, 0.f, 0.f};
            acc1 = __builtin_amdgcn_mfma_f32_16x16x32_bf16(Am0, B[0][0][0], acc1, 0, 0, 0);
            acc1 = __builtin_amdgcn_mfma_f32_16x16x32_bf16(Am0, B[0][0][1], acc1, 0, 0, 0);
            acc1 = __builtin_amdgcn_mfma_f32_16x16x32_bf16(Am1, B[0][1][0], acc1, 0, 0, 0);
            acc1 = __builtin_amdgcn_mfma_f32_16x16x32_bf16(Am1, B[0][1][1], acc1, 0, 0, 0);
            acc2 = __builtin_amdgcn_mfma_f32_16x16x32_bf16(Ah0, B[1][0][0], acc2, 0, 0, 0);
            acc2 = __builtin_amdgcn_mfma_f32_16x16x32_bf16(Ah0, B[1][0][1], acc2, 0, 0, 0);
            acc2 = __builtin_amdgcn_mfma_f32_16x16x32_bf16(Ah1, B[1][1][0], acc2, 0, 0, 0);
            acc2 = __builtin_amdgcn_mfma_f32_16x16x32_bf16(Ah1, B[1][1][1], acc2, 0, 0, 0);
            acc3 = __builtin_amdgcn_mfma_f32_16x16x32_bf16(Ah0, B[2][0][0], acc3, 0, 0, 0);
            acc3 = __builtin_amdgcn_mfma_f32_16x16x32_bf16(Ah0, B[2][0][1], acc3, 0, 0, 0);
            acc3 = __builtin_amdgcn_mfma_f32_16x16x32_bf16(Ah1, B[2][1][0], acc3, 0, 0, 0);
            acc3 = __builtin_amdgcn_mfma_f32_16x16x32_bf16(Ah1, B[2][1][1], acc3, 0, 0, 0);
            int nrow = nbase + ng * 16 + quad * 4;
#pragma unroll
            for (int r = 0; r < 4; ++r) {
                int n = nrow + r;
                if (n < N_NODES) {
                    float dw = degw[n];
                    float v = acc1[r] + dw * bb1 + acc3[r] + bb3 - acc2[r] * dw;
                    h[(size_t)n * H + f] = f2bf(fmaxf(v, 0.0f));
                }
            }
        }
    }
}

// ---------------- fused mean-pool + MLP head (batch is sorted) ----------------
__device__ __forceinline__ int lower_bound(const int* __restrict__ arr, int n, int key) {
    int lo = 0, hi = n;
    while (lo < hi) {
        int mid = (lo + hi) >> 1;
        if (arr[mid] < key) lo = mid + 1; else hi = mid;
    }
    return lo;
}

__global__ __launch_bounds__(256) void poolhead_kernel(
    const ushort* __restrict__ h, const int* __restrict__ batch,
    const float* __restrict__ Wf1, const float* __restrict__ bf1v,
    const float* __restrict__ Wf2, const float* __restrict__ bf2v,
    float* __restrict__ out) {
    __shared__ float psum[4][H];
    __shared__ float gx[H];
    __shared__ float hid[2 * H];
    int g = blockIdx.x, t = threadIdx.x;
    int s = lower_bound(batch, N_NODES, g);
    int e = lower_bound(batch, N_NODES, g + 1);
    int lane = t & 63, wv = t >> 6;
    int o = lane & 7;
    int nd = t >> 3;
    float acc[8] = {0.f, 0.f, 0.f, 0.f, 0.f, 0.f, 0.f, 0.f};
    for (int n = s + nd; n < e; n += 32) {
        ush8 v = *(const ush8*)&h[(size_t)n * H + o * 8];
#pragma unroll
        for (int i = 0; i < 8; ++i) acc[i] += bf2f((ushort)v[i]);
    }
#pragma unroll
    for (int i = 0; i < 8; ++i) {
        acc[i] += __shfl_xor(acc[i], 8);
        acc[i] += __shfl_xor(acc[i], 16);
        acc[i] += __shfl_xor(acc[i], 32);
    }
    if (lane < 8) {
#pragma unroll
        for (int i = 0; i < 8; ++i) psum[wv][o * 8 + i] = acc[i];
    }
    __syncthreads();
    if (t < H) {
        float c = (float)(e - s);
        gx[t] = (psum[0][t] + psum[1][t] + psum[2][t] + psum[3][t]) / fmaxf(c, 1.0f);
    }
    __syncthreads();
    if (t < 2 * H) {
        float acc2 = bf1v[t];
        for (int k = 0; k < H; ++k) acc2 += gx[k] * Wf1[k * 2 * H + t];
        hid[t] = fmaxf(acc2, 0.0f);
    }
    __syncthreads();
    if (t < NUM_CLASS) {
        float o2 = bf2v[t];
        for (int k = 0; k < 2 * H; ++k) o2 += hid[k] * Wf2[k * NUM_CLASS + t];
        out[g * NUM_CLASS + t] = o2;
    }
}

extern "C" void kernel_launch(void* const* d_in, const int* in_sizes, int n_in,
                              void* d_out, int out_size, void* d_ws, size_t ws_size,
                              hipStream_t stream) {
    const float* x    = (const float*)d_in[0];
    const int*  ei    = (const int*)d_in[1];
    const int*  batch = (const int*)d_in[2];
    const float* ea   = (const float*)d_in[3];
    const float* Wemb = (const float*)d_in[4];
    const float* bemb = (const float*)d_in[5];
    const float* pW1  = (const float*)d_in[6];
    const float* pb1  = (const float*)d_in[7];
    const float* pW2  = (const float*)d_in[8];
    const float* pW3  = (const float*)d_in[9];
    const float* pb3  = (const float*)d_in[10];
    const float* Wf1  = (const float*)d_in[11];
    const float* bf1v = (const float*)d_in[12];
    const float* Wf2  = (const float*)d_in[13];
    const float* bf2v = (const float*)d_in[14];
    float* out = (float*)d_out;

    const int* src = ei;
    const int* dst = ei + N_EDGES;

    // ---- workspace layout ----
    const size_t NH = (size_t)N_NODES * H;
    char* p = (char*)d_ws;
    ushort* h       = (ushort*)p;            p += NH * 2;               // 12.8 MB
    ushort* m       = (ushort*)p;            p += NH * 2;               // 12.8 MB
    unsigned* epack = (unsigned*)p;          p += (size_t)N_EDGES * 4;  // 6.4 MB
    int*   histM    = (int*)p;               p += MHIST * 4;
    int*   bkt_ptr  = (int*)p;               p += (NBKT + 1) * 4;
    int*   row_ptr  = (int*)p;               p += (N_NODES + 1) * 4;
    float* degw     = (float*)p;             p += N_NODES * 4;
    float* Gbuf     = (float*)p;             p += 3 * 256 * 4;
    float* Cbuf     = (float*)p;             p += 3 * 64 * 4;
    // staging overlays m/h (dead until layer1; build completes first)
    unsigned* eb_se = (unsigned*)m;          // 6.4 MB (m region: 12.8 MB)
    ushort*  eb_dst = (ushort*)h;            // 3.2 MB (h region: 12.8 MB)

    // ---- CSR build: 3 dispatches (precomp in hist1, full scan in scatter1) ----
    hist1_kernel<<<NBLK, 256, 0, stream>>>(dst, histM, Wemb, bemb, pW1, pb1, pW2, pW3, pb3,
                                           Gbuf, Cbuf);
    scatter1_kernel<<<NBLK, 256, 0, stream>>>(src, dst, ea, histM, eb_se, eb_dst, bkt_ptr);
    bucket_kernel<<<NBKT, 512, 0, stream>>>(bkt_ptr, eb_se, eb_dst, row_ptr, degw, epack);

    // ---- layer 1: fused x-gather + combine (1 dispatch) ----
    layer1_kernel<<<(N_NODES + 3) / 4, 256, 0, stream>>>(row_ptr, epack, x, degw,
                                                         Gbuf, Cbuf, h);

    // ---- layers 2,3: gather m from h, then MFMA lin in-place ----
    for (int l = 1; l < LAYERS; ++l) {
        gather_kernel<<<(N_NODES + 3) / 4, 256, 0, stream>>>(row_ptr, epack, h, m);
        linC_kernel<<<LINC_GRID, 256, 0, stream>>>(
            h, m, degw,
            pW1 + (size_t)l * H * H, pb1 + (size_t)l * H,
            pW2 + (size_t)l * H * H,
            pW3 + (size_t)l * H * H, pb3 + (size_t)l * H);
    }

    poolhead_kernel<<<N_GRAPHS, 256, 0, stream>>>(h, batch, Wf1, bf1v, Wf2, bf2v, out);
}